// Round 15
// baseline (339.421 us; speedup 1.0000x reference)
//
#include <hip/hip_runtime.h>
#include <hip/hip_bf16.h>

// Shapes (fixed): B=8,C=256,H=64,W=128,P=4,E=DM=128,N=512,DI=256,DS=16,DC=4,DR=8,NG=128,S=2
#define HW2 32768   // 128*256 output spatial per (b,channel)

typedef __attribute__((ext_vector_type(8))) short short8v;
typedef __attribute__((ext_vector_type(4))) float f32x4;

__device__ __forceinline__ float siluf(float x){ return x / (1.f + __expf(-x)); }
__device__ __forceinline__ float geluf(float v){
  float t = 0.7978845608028654f * fmaf(0.044715f*v*v, v, v);
  t = fminf(fmaxf(t, -15.f), 15.f);
  float e = __expf(2.f*t);
  return 0.5f*v*(1.f + (e-1.f)/(e+1.f));
}
__device__ __forceinline__ ushort bf16rne(float f){
  unsigned u = __float_as_uint(f);
  unsigned r = (u + 0x7fffu + ((u >> 16) & 1u)) >> 16;
  return (ushort)r;
}
__device__ __forceinline__ float bf2f(ushort u){ return __uint_as_float(((unsigned)u) << 16); }
__device__ __forceinline__ void split2(float v, ushort& h, ushort& lo){
  h = bf16rne(v);
  lo = bf16rne(v - bf2f(h));
}

// ---------------- merged prep: ubf halo zero + conv/ffn/lin weight bf16 packs ----------------
__global__ __launch_bounds__(256) void k_prep(uint4* __restrict__ ubf4,
                                              const float* __restrict__ cw, ushort* __restrict__ wbf,
                                              const float* __restrict__ w1, const float* __restrict__ w2,
                                              ushort* __restrict__ wpad,
                                              const float* __restrict__ lw, ushort* __restrict__ lwbf){
  int bid = blockIdx.x;
  int tid = threadIdx.x;
  if (bid < 32) {                       // zero ubf halo borders
    uint4 z = make_uint4(0,0,0,0);
    size_t base4 = (size_t)bid * 34320;
    for (int i = tid; i < 1552; i += 256) {
      size_t off;
      if (i < 520)       off = i;
      else if (i < 1040) off = 33800 + (i - 520);
      else {
        int j = i - 1040;
        int row = 1 + (j >> 3);
        int colsel = (j >> 2) & 1, q = j & 3;
        off = (size_t)row*520 + colsel*516 + q;
      }
      ubf4[base4 + off] = z;
    }
  } else if (bid < 2336) {              // conv weights: frag-linear [(ocg*4+ec)][tap9][f4][lane64][8e]
    int idx = (bid - 32)*256 + tid;     // 589824
    int j    = idx & 7;
    int lane = (idx >> 3) & 63;
    int f    = (idx >> 9) & 3;
    int tap  = (idx >> 11) % 9;
    int rest = idx / 18432;
    int ec = rest & 3, ocg = rest >> 2;
    int o = ocg*64 + f*16 + (lane & 15);
    int e = ec*32 + (lane >> 4)*8 + j;
    wbf[idx] = bf16rne(cw[((size_t)o*128 + e)*9 + tap]);
  } else if (bid < 2472) {              // FFN weights padded [2][128][136]
    int idx = (bid - 2336)*256 + tid;   // 34816
    int which = idx / 17408;
    int rem = idx - which*17408;
    int e = rem / 136, k = rem - e*136;
    const float* s = which ? w2 : w1;
    wpad[idx] = (k < 128) ? bf16rne(s[e*128 + k]) : (ushort)0;
  } else {                              // lin weights bf16
    int i = (bid - 2472)*256 + tid;     // 1048576 float4s
    float4 v = reinterpret_cast<const float4*>(lw)[i];
    uint2 u;
    u.x = (uint)bf16rne(v.x) | ((uint)bf16rne(v.y) << 16);
    u.y = (uint)bf16rne(v.z) | ((uint)bf16rne(v.w) << 16);
    reinterpret_cast<uint2*>(lwbf)[i] = u;
  }
}

// ---------------- patch embed via bf16x3 MFMA, split-K=16 -> part[ks][4096][128] ----------------
__global__ __launch_bounds__(256) void k_patchm(const float* __restrict__ x, const float* __restrict__ pw,
                                                float* __restrict__ part){
  __shared__ ushort Ah[4096], Al[4096], Wh[4096], Wl[4096];  // frag-linear per 32-k chunk
  int m0 = blockIdx.x * 128;
  int ks = blockIdx.y;                 // 0..15
  int tid = threadIdx.x;
  int l = tid & 63, wv = tid >> 6;
  int wm = wv >> 1, we = wv & 1;
  int lj = l & 15, lg = l >> 4;
  f32x4 acc[4][4];
  #pragma unroll
  for (int a = 0; a < 4; ++a)
    #pragma unroll
    for (int b = 0; b < 4; ++b)
      acc[a][b] = (f32x4){0.f,0.f,0.f,0.f};
  int kbase = ks * 256;

  for (int it = 0; it < 8; ++it) {
    int k0 = kbase + it*32;
    __syncthreads();
    #pragma unroll
    for (int q = 0; q < 4; ++q) {
      int flat = q*256 + tid;
      int row = flat & 127, kk4 = flat >> 7;
      int m = m0 + row;
      int bb = m >> 9, ll = m & 511;
      int hp = ll >> 5, wp = ll & 31;
      int k = k0 + kk4*4;
      int c = k >> 4, i2 = (k >> 2) & 3;
      float4 v = *reinterpret_cast<const float4*>(x + (((bb*256 + c)*64 + hp*4 + i2)*128 + wp*4));
      ushort h0,h1,h2,h3,q0,q1,q2,q3;
      split2(v.x,h0,q0); split2(v.y,h1,q1); split2(v.z,h2,q2); split2(v.w,h3,q3);
      uint2 uh, ul;
      uh.x = (uint)h0 | ((uint)h1 << 16); uh.y = (uint)h2 | ((uint)h3 << 16);
      ul.x = (uint)q0 | ((uint)q1 << 16); ul.y = (uint)q2 | ((uint)q3 << 16);
      int lane = ((kk4 >> 1) << 4) | (row & 15);
      int dst = ((row >> 4)*64 + lane)*8 + (kk4 & 1)*4;
      *reinterpret_cast<uint2*>(Ah + dst) = uh;
      *reinterpret_cast<uint2*>(Al + dst) = ul;
    }
    #pragma unroll
    for (int q = 0; q < 4; ++q) {
      int flat = q*256 + tid;
      int e = flat >> 3, kk4 = flat & 7;
      float4 v = *reinterpret_cast<const float4*>(pw + (size_t)e*4096 + k0 + kk4*4);
      ushort h0,h1,h2,h3,q0,q1,q2,q3;
      split2(v.x,h0,q0); split2(v.y,h1,q1); split2(v.z,h2,q2); split2(v.w,h3,q3);
      uint2 uh, ul;
      uh.x = (uint)h0 | ((uint)h1 << 16); uh.y = (uint)h2 | ((uint)h3 << 16);
      ul.x = (uint)q0 | ((uint)q1 << 16); ul.y = (uint)q2 | ((uint)q3 << 16);
      int lane = ((kk4 >> 1) << 4) | (e & 15);
      int dst = ((e >> 4)*64 + lane)*8 + (kk4 & 1)*4;
      *reinterpret_cast<uint2*>(Wh + dst) = uh;
      *reinterpret_cast<uint2*>(Wl + dst) = ul;
    }
    __syncthreads();

    short8v ah[4], al_[4], wh[4], wl_[4];
    #pragma unroll
    for (int f = 0; f < 4; ++f) {
      ah[f]  = *reinterpret_cast<const short8v*>(Ah + ((wm*4 + f)*64 + l)*8);
      al_[f] = *reinterpret_cast<const short8v*>(Al + ((wm*4 + f)*64 + l)*8);
      wh[f]  = *reinterpret_cast<const short8v*>(Wh + ((we*4 + f)*64 + l)*8);
      wl_[f] = *reinterpret_cast<const short8v*>(Wl + ((we*4 + f)*64 + l)*8);
    }
    #pragma unroll
    for (int fo = 0; fo < 4; ++fo)
      #pragma unroll
      for (int fj = 0; fj < 4; ++fj) {
        acc[fo][fj] = __builtin_amdgcn_mfma_f32_16x16x32_bf16(ah[fo],  wh[fj],  acc[fo][fj], 0, 0, 0);
        acc[fo][fj] = __builtin_amdgcn_mfma_f32_16x16x32_bf16(ah[fo],  wl_[fj], acc[fo][fj], 0, 0, 0);
        acc[fo][fj] = __builtin_amdgcn_mfma_f32_16x16x32_bf16(al_[fo], wh[fj],  acc[fo][fj], 0, 0, 0);
      }
  }
  float* pb = part + (size_t)ks*524288;
  #pragma unroll
  for (int fo = 0; fo < 4; ++fo) {
    int m = m0 + wm*64 + fo*16 + lg*4;
    #pragma unroll
    for (int fj = 0; fj < 4; ++fj) {
      int e = we*64 + fj*16 + lj;
      f32x4 a = acc[fo][fj];
      pb[(size_t)(m+0)*128 + e] = a.x;
      pb[(size_t)(m+1)*128 + e] = a.y;
      pb[(size_t)(m+2)*128 + e] = a.z;
      pb[(size_t)(m+3)*128 + e] = a.w;
    }
  }
}

// ---------------- reduce 16 K-split partials + bias -> t ----------------
__global__ __launch_bounds__(256) void k_tred(const float* __restrict__ part, const float* __restrict__ pb,
                                              float* __restrict__ t){
  int i = blockIdx.x*256 + threadIdx.x;    // 131072 float4s
  const float4* p4 = reinterpret_cast<const float4*>(part);
  float4 s = reinterpret_cast<const float4*>(pb)[i & 31];
  #pragma unroll
  for (int ks = 0; ks < 16; ++ks) {
    float4 v = p4[(size_t)ks*131072 + i];
    s.x += v.x; s.y += v.y; s.z += v.z; s.w += v.w;
  }
  reinterpret_cast<float4*>(t)[i] = s;
}

// ---------------- in_proj via bf16x3 MFMA: xz(4096x512) = t(4096x128) @ W(512x128)^T ----------------
__global__ __launch_bounds__(256) void k_iproj(const float* __restrict__ t, const float* __restrict__ W,
                                               float* __restrict__ xz){
  __shared__ ushort Ah[4096], Al[4096], Wh[4096], Wl[4096];
  int m0 = blockIdx.x * 128;
  int n0 = blockIdx.y * 128;
  int tid = threadIdx.x;
  int l = tid & 63, wv = tid >> 6;
  int wm = wv >> 1, we = wv & 1;
  int lj = l & 15, lg = l >> 4;
  f32x4 acc[4][4];
  #pragma unroll
  for (int a = 0; a < 4; ++a)
    #pragma unroll
    for (int b = 0; b < 4; ++b)
      acc[a][b] = (f32x4){0.f,0.f,0.f,0.f};

  for (int it = 0; it < 4; ++it) {
    int k0 = it*32;
    __syncthreads();
    #pragma unroll
    for (int q = 0; q < 4; ++q) {
      int flat = q*256 + tid;
      int row = flat & 127, kk4 = flat >> 7;
      float4 v = *reinterpret_cast<const float4*>(t + (size_t)(m0 + row)*128 + k0 + kk4*4);
      ushort h0,h1,h2,h3,q0,q1,q2,q3;
      split2(v.x,h0,q0); split2(v.y,h1,q1); split2(v.z,h2,q2); split2(v.w,h3,q3);
      uint2 uh, ul;
      uh.x = (uint)h0 | ((uint)h1 << 16); uh.y = (uint)h2 | ((uint)h3 << 16);
      ul.x = (uint)q0 | ((uint)q1 << 16); ul.y = (uint)q2 | ((uint)q3 << 16);
      int lane = ((kk4 >> 1) << 4) | (row & 15);
      int dst = ((row >> 4)*64 + lane)*8 + (kk4 & 1)*4;
      *reinterpret_cast<uint2*>(Ah + dst) = uh;
      *reinterpret_cast<uint2*>(Al + dst) = ul;
    }
    #pragma unroll
    for (int q = 0; q < 4; ++q) {
      int flat = q*256 + tid;
      int e = flat >> 3, kk4 = flat & 7;
      float4 v = *reinterpret_cast<const float4*>(W + (size_t)(n0 + e)*128 + k0 + (kk4 & 7)*4);
      ushort h0,h1,h2,h3,q0,q1,q2,q3;
      split2(v.x,h0,q0); split2(v.y,h1,q1); split2(v.z,h2,q2); split2(v.w,h3,q3);
      uint2 uh, ul;
      uh.x = (uint)h0 | ((uint)h1 << 16); uh.y = (uint)h2 | ((uint)h3 << 16);
      ul.x = (uint)q0 | ((uint)q1 << 16); ul.y = (uint)q2 | ((uint)q3 << 16);
      int lane = ((kk4 >> 1) << 4) | (e & 15);
      int dst = ((e >> 4)*64 + lane)*8 + (kk4 & 1)*4;
      *reinterpret_cast<uint2*>(Wh + dst) = uh;
      *reinterpret_cast<uint2*>(Wl + dst) = ul;
    }
    __syncthreads();

    short8v ah[4], al_[4], wh[4], wl_[4];
    #pragma unroll
    for (int f = 0; f < 4; ++f) {
      ah[f]  = *reinterpret_cast<const short8v*>(Ah + ((wm*4 + f)*64 + l)*8);
      al_[f] = *reinterpret_cast<const short8v*>(Al + ((wm*4 + f)*64 + l)*8);
      wh[f]  = *reinterpret_cast<const short8v*>(Wh + ((we*4 + f)*64 + l)*8);
      wl_[f] = *reinterpret_cast<const short8v*>(Wl + ((we*4 + f)*64 + l)*8);
    }
    #pragma unroll
    for (int fo = 0; fo < 4; ++fo)
      #pragma unroll
      for (int fj = 0; fj < 4; ++fj) {
        acc[fo][fj] = __builtin_amdgcn_mfma_f32_16x16x32_bf16(ah[fo],  wh[fj],  acc[fo][fj], 0, 0, 0);
        acc[fo][fj] = __builtin_amdgcn_mfma_f32_16x16x32_bf16(ah[fo],  wl_[fj], acc[fo][fj], 0, 0, 0);
        acc[fo][fj] = __builtin_amdgcn_mfma_f32_16x16x32_bf16(al_[fo], wh[fj],  acc[fo][fj], 0, 0, 0);
      }
  }
  #pragma unroll
  for (int fo = 0; fo < 4; ++fo) {
    int m = m0 + wm*64 + fo*16 + lg*4;
    #pragma unroll
    for (int fj = 0; fj < 4; ++fj) {
      int n = n0 + we*64 + fj*16 + lj;
      f32x4 a = acc[fo][fj];
      xz[(size_t)(m+0)*512 + n] = a.x;
      xz[(size_t)(m+1)*512 + n] = a.y;
      xz[(size_t)(m+2)*512 + n] = a.z;
      xz[(size_t)(m+3)*512 + n] = a.w;
    }
  }
}

// ---------------- out_proj v2: m-tile 64, grid 64, 4 waves (wn x4, 64m x 32n each) ----------------
__global__ __launch_bounds__(256) void k_oproj(const float* __restrict__ y, const float* __restrict__ W,
                                               ushort* __restrict__ ybfT){
  __shared__ ushort Ah[2048], Al[2048], Wh[4096], Wl[4096];
  int m0 = blockIdx.x * 64;
  int tid = threadIdx.x;
  int l = tid & 63, wn = tid >> 6;     // wn 0..3
  int lj = l & 15, lg = l >> 4;
  f32x4 acc[4][2];
  #pragma unroll
  for (int a = 0; a < 4; ++a)
    #pragma unroll
    for (int b = 0; b < 2; ++b)
      acc[a][b] = (f32x4){0.f,0.f,0.f,0.f};

  for (int it = 0; it < 8; ++it) {
    int k0 = it*32;
    __syncthreads();
    // stage A: 64 rows x 8 kk4 = 512 tasks
    #pragma unroll
    for (int q = 0; q < 2; ++q) {
      int flat = q*256 + tid;
      int row = flat & 63, kk4 = flat >> 6;
      float4 v = *reinterpret_cast<const float4*>(y + (size_t)(m0 + row)*256 + k0 + kk4*4);
      ushort h0,h1,h2,h3,q0,q1,q2,q3;
      split2(v.x,h0,q0); split2(v.y,h1,q1); split2(v.z,h2,q2); split2(v.w,h3,q3);
      uint2 uh, ul;
      uh.x = (uint)h0 | ((uint)h1 << 16); uh.y = (uint)h2 | ((uint)h3 << 16);
      ul.x = (uint)q0 | ((uint)q1 << 16); ul.y = (uint)q2 | ((uint)q3 << 16);
      int lane = ((kk4 >> 1) << 4) | (row & 15);
      int dst = ((row >> 4)*64 + lane)*8 + (kk4 & 1)*4;
      *reinterpret_cast<uint2*>(Ah + dst) = uh;
      *reinterpret_cast<uint2*>(Al + dst) = ul;
    }
    // stage W: 128 rows x 8 kk4 = 1024 tasks
    #pragma unroll
    for (int q = 0; q < 4; ++q) {
      int flat = q*256 + tid;
      int e = flat >> 3, kk4 = flat & 7;
      float4 v = *reinterpret_cast<const float4*>(W + (size_t)e*256 + k0 + kk4*4);
      ushort h0,h1,h2,h3,q0,q1,q2,q3;
      split2(v.x,h0,q0); split2(v.y,h1,q1); split2(v.z,h2,q2); split2(v.w,h3,q3);
      uint2 uh, ul;
      uh.x = (uint)h0 | ((uint)h1 << 16); uh.y = (uint)h2 | ((uint)h3 << 16);
      ul.x = (uint)q0 | ((uint)q1 << 16); ul.y = (uint)q2 | ((uint)q3 << 16);
      int lane = ((kk4 >> 1) << 4) | (e & 15);
      int dst = ((e >> 4)*64 + lane)*8 + (kk4 & 1)*4;
      *reinterpret_cast<uint2*>(Wh + dst) = uh;
      *reinterpret_cast<uint2*>(Wl + dst) = ul;
    }
    __syncthreads();

    short8v ah[4], al_[4], wh[2], wl_[2];
    #pragma unroll
    for (int f = 0; f < 4; ++f) {
      ah[f]  = *reinterpret_cast<const short8v*>(Ah + (f*64 + l)*8);
      al_[f] = *reinterpret_cast<const short8v*>(Al + (f*64 + l)*8);
    }
    #pragma unroll
    for (int f = 0; f < 2; ++f) {
      wh[f]  = *reinterpret_cast<const short8v*>(Wh + ((wn*2 + f)*64 + l)*8);
      wl_[f] = *reinterpret_cast<const short8v*>(Wl + ((wn*2 + f)*64 + l)*8);
    }
    #pragma unroll
    for (int fo = 0; fo < 4; ++fo)
      #pragma unroll
      for (int fj = 0; fj < 2; ++fj) {
        acc[fo][fj] = __builtin_amdgcn_mfma_f32_16x16x32_bf16(ah[fo],  wh[fj],  acc[fo][fj], 0, 0, 0);
        acc[fo][fj] = __builtin_amdgcn_mfma_f32_16x16x32_bf16(ah[fo],  wl_[fj], acc[fo][fj], 0, 0, 0);
        acc[fo][fj] = __builtin_amdgcn_mfma_f32_16x16x32_bf16(al_[fo], wh[fj],  acc[fo][fj], 0, 0, 0);
      }
  }
  #pragma unroll
  for (int fo = 0; fo < 4; ++fo) {
    int m = m0 + fo*16 + lg*4;
    int b = m >> 9, n = m & 511;
    #pragma unroll
    for (int fj = 0; fj < 2; ++fj) {
      int e = wn*32 + fj*16 + lj;
      f32x4 a = acc[fo][fj];
      uint2 u;
      u.x = (uint)bf16rne(a.x) | ((uint)bf16rne(a.y) << 16);
      u.y = (uint)bf16rne(a.z) | ((uint)bf16rne(a.w) << 16);
      *reinterpret_cast<uint2*>(ybfT + ((size_t)b*128 + e)*512 + n) = u;
    }
  }
}

// ---------------- fused conv1d+silu -> xc, then x_proj + dt_proj + softplus ----------------
__global__ __launch_bounds__(256) void k_cxp(const float* __restrict__ xz, const float* __restrict__ w1d,
                                             const float* __restrict__ c1b,
                                             const float* __restrict__ xpw,
                                             const float* __restrict__ dtw, const float* __restrict__ dtb,
                                             float* __restrict__ xc, float* __restrict__ dbl,
                                             float* __restrict__ dt){
  __shared__ __align__(16) float sxc[256];
  __shared__ float sdbl[40];
  int bl = blockIdx.x;         // (b,l) 0..4095
  int bb = bl >> 9, ll = bl & 511;
  int tid = threadIdx.x;
  float s = c1b[tid];
  #pragma unroll
  for (int k = 0; k < 4; ++k) {
    int ls = ll - 3 + k;
    if (ls >= 0) s = fmaf(xz[((size_t)(bb*512 + ls))*512 + tid], w1d[tid*4 + k], s);
  }
  float xcv = s / (1.f + __expf(-s));
  xc[(size_t)bl*256 + tid] = xcv;
  sxc[tid] = xcv;
  __syncthreads();
  if (tid < 160) {
    int g = tid >> 2, kq = tid & 3;
    const float4* wr = reinterpret_cast<const float4*>(xpw + g*256) + kq;
    const float4* xr = reinterpret_cast<const float4*>(sxc) + kq;
    float sv = 0.f;
    #pragma unroll
    for (int i = 0; i < 16; ++i) {
      float4 w = wr[i*4], xv = xr[i*4];
      sv += w.x*xv.x + w.y*xv.y + w.z*xv.z + w.w*xv.w;
    }
    sv += __shfl_xor(sv, 1);
    sv += __shfl_xor(sv, 2);
    if (kq == 0) {
      sdbl[g] = sv;
      dbl[(size_t)bl*40 + g] = sv;
    }
  }
  __syncthreads();
  float sd = dtb[tid];
  const float* wr = dtw + tid*8;
  #pragma unroll
  for (int r = 0; r < 8; ++r) sd = fmaf(sdbl[r], wr[r], sd);
  float sp = (sd > 20.f) ? sd : log1pf(__expf(sd));
  dt[(size_t)bl*256 + tid] = sp;
}

// ---------------- chunk-parallel selective scan (LDS-preloaded) ----------------
__global__ __launch_bounds__(256) void k_scanA(const float* __restrict__ dt, const float* __restrict__ dbl,
                                               const float* __restrict__ xc, const float* __restrict__ A_log,
                                               float* __restrict__ aprod, float* __restrict__ hend){
  __shared__ float sdt[32][16], sxc[32][16], sB[32][16];
  int tid = threadIdx.x;
  int bg = blockIdx.x;            // b*16 + dgrp
  int ch = blockIdx.y;
  int bb = bg >> 4, dgrp = bg & 15;
  int l0 = ch*32;
  #pragma unroll
  for (int it = 0; it < 2; ++it) {
    int idx = it*256 + tid;       // 0..511
    int t = idx >> 4, dd = idx & 15;
    int base = bb*512 + l0 + t;
    sdt[t][dd] = dt[(size_t)base*256 + dgrp*16 + dd];
    sxc[t][dd] = xc[(size_t)base*256 + dgrp*16 + dd];
    sB [t][dd] = dbl[(size_t)base*40 + 8 + dd];
  }
  __syncthreads();
  int n = tid & 15, dloc = tid >> 4;
  float Ac = -__expf(A_log[(dgrp*16 + dloc)*16 + n]);
  float a = 1.f, h = 0.f;
  #pragma unroll
  for (int t = 0; t < 32; ++t) {
    float dtv = sdt[t][dloc], xcv = sxc[t][dloc], Bv = sB[t][n];
    float dA = __expf(dtv*Ac);
    h = fmaf(dA, h, dtv*Bv*xcv);
    a *= dA;
  }
  aprod[(size_t)(bg*16 + ch)*256 + tid] = a;
  hend [(size_t)(bg*16 + ch)*256 + tid] = h;
}

// scanC with fused cross-chunk prefix
__global__ __launch_bounds__(256) void k_scanC(const float* __restrict__ dt, const float* __restrict__ dbl,
                                               const float* __restrict__ xc, const float* __restrict__ xz,
                                               const float* __restrict__ A_log, const float* __restrict__ Dp,
                                               const float* __restrict__ aprod, const float* __restrict__ hend,
                                               float* __restrict__ y){
  __shared__ float sdt[32][16], sxc[32][16], sB[32][16], sC[32][16], sz[32][16];
  int tid = threadIdx.x;
  int bg = blockIdx.x;
  int ch = blockIdx.y;
  int bb = bg >> 4, dgrp = bg & 15;
  int l0 = ch*32;
  #pragma unroll
  for (int it = 0; it < 2; ++it) {
    int idx = it*256 + tid;
    int t = idx >> 4, dd = idx & 15;
    int base = bb*512 + l0 + t;
    sdt[t][dd] = dt[(size_t)base*256 + dgrp*16 + dd];
    sxc[t][dd] = xc[(size_t)base*256 + dgrp*16 + dd];
    sB [t][dd] = dbl[(size_t)base*40 + 8  + dd];
    sC [t][dd] = dbl[(size_t)base*40 + 24 + dd];
    sz [t][dd] = xz[(size_t)base*512 + 256 + dgrp*16 + dd];
  }
  float h = 0.f;
  for (int cc = 0; cc < ch; ++cc) {
    size_t idx = (size_t)(bg*16 + cc)*256 + tid;
    h = fmaf(aprod[idx], h, hend[idx]);
  }
  __syncthreads();
  int n = tid & 15, dloc = tid >> 4;
  int d = dgrp*16 + dloc;
  float Ac = -__expf(A_log[d*16 + n]);
  float Dv = Dp[d];
  #pragma unroll 4
  for (int t = 0; t < 32; ++t) {
    float dtv = sdt[t][dloc], xcv = sxc[t][dloc];
    float Bv = sB[t][n], Cv = sC[t][n];
    float dA = __expf(dtv*Ac);
    h = fmaf(dA, h, dtv*Bv*xcv);
    float yp = h*Cv;
    yp += __shfl_xor(yp, 1, 16);
    yp += __shfl_xor(yp, 2, 16);
    yp += __shfl_xor(yp, 4, 16);
    yp += __shfl_xor(yp, 8, 16);
    if (n == 0) {
      float zv = sz[t][dloc];
      y[(size_t)(bb*512 + l0 + t)*256 + d] = (yp + Dv*xcv) * (zv / (1.f + __expf(-zv)));
    }
  }
}

// ---------------- lin via bf16 MFMA + bias + pixel-shuffle -> padded bf16 ubf ----------------
__global__ __launch_bounds__(512) void k_linm(const ushort* __restrict__ ybfT, const ushort* __restrict__ lwbf,
                                              const float* __restrict__ lb, ushort* __restrict__ ubf){
  __shared__ ushort As[128*88];
  __shared__ ushort Bs[128*88];
  int m0 = blockIdx.x * 128;
  int b  = blockIdx.y;
  int tid = threadIdx.x;
  int l = tid & 63, wv = tid >> 6;
  int wm = wv & 3, we = wv >> 2;
  int lj = l & 15, lg = l >> 4;
  f32x4 acc[4][2];
  #pragma unroll
  for (int fo = 0; fo < 4; ++fo)
    #pragma unroll
    for (int fj = 0; fj < 2; ++fj)
      acc[fo][fj] = (f32x4){0.f,0.f,0.f,0.f};

  for (int k0 = 0; k0 < 512; k0 += 64) {
    __syncthreads();
    #pragma unroll
    for (int it = 0; it < 2; ++it) {
      int flat = it*512 + tid;        // 0..1023
      int e = flat >> 3, kc8 = flat & 7;
      *reinterpret_cast<uint4*>(&As[e*88 + kc8*8]) =
        *reinterpret_cast<const uint4*>(ybfT + ((size_t)b*128 + e)*512 + k0 + kc8*8);
      *reinterpret_cast<uint4*>(&Bs[e*88 + kc8*8]) =
        *reinterpret_cast<const uint4*>(lwbf + (size_t)(m0 + e)*512 + k0 + kc8*8);
    }
    __syncthreads();
    #pragma unroll
    for (int kc = 0; kc < 2; ++kc) {
      short8v af[4], bq[2];
      #pragma unroll
      for (int fo = 0; fo < 4; ++fo)
        af[fo] = *reinterpret_cast<const short8v*>(&As[(we*64 + fo*16 + lj)*88 + kc*32 + lg*8]);
      #pragma unroll
      for (int fj = 0; fj < 2; ++fj)
        bq[fj] = *reinterpret_cast<const short8v*>(&Bs[(wm*32 + fj*16 + lj)*88 + kc*32 + lg*8]);
      #pragma unroll
      for (int fo = 0; fo < 4; ++fo)
        #pragma unroll
        for (int fj = 0; fj < 2; ++fj)
          acc[fo][fj] = __builtin_amdgcn_mfma_f32_16x16x32_bf16(af[fo], bq[fj], acc[fo][fj], 0, 0, 0);
    }
  }
  #pragma unroll
  for (int fj = 0; fj < 2; ++fj) {
    int m = m0 + wm*32 + fj*16 + lj;
    float bias = lb[m];
    int hh = ((m >> 9) << 2) + ((m >> 2) & 3);
    int ww = (((m >> 4) & 31) << 2) + (m & 3);
    #pragma unroll
    for (int fo = 0; fo < 4; ++fo) {
      int eg = we*2 + (fo >> 1);
      int e5 = ((fo & 1) << 4) + (lg << 2);
      f32x4 a = acc[fo][fj];
      uint2 u;
      u.x = (uint)bf16rne(a.x + bias) | ((uint)bf16rne(a.y + bias) << 16);
      u.y = (uint)bf16rne(a.z + bias) | ((uint)bf16rne(a.w + bias) << 16);
      *reinterpret_cast<uint2*>(ubf + ((((size_t)b*4 + eg)*66 + hh + 1)*130 + ww + 1)*32 + e5) = u;
    }
  }
}

// ---------------- conv3x3 v7: r14 tile, but 36.9 KB LDS (sequential o-halves) -> 4 blocks/CU --------
// grid (h2=32, bz=32: bb*4+op). 512 thr = 8 waves (2hr x 4wseg32). Bit-identical accumulation order.
__global__ __launch_bounds__(512) void k_conv3m(const ushort* __restrict__ ubf, const ushort* __restrict__ wbf,
                                                const float* __restrict__ cb, ushort* __restrict__ cbf){
  __shared__ ushort wlds[18432];    // one 64-o half: [9 tap][4 f][64 lane][8 e] (36.9 KB)
  int h2 = blockIdx.x;              // 0..31
  int bz = blockIdx.y;
  int bb = bz >> 2, op = bz & 3;    // batch, 128-o pair
  int tid = threadIdx.x;
  int l   = tid & 63;
  int wv  = tid >> 6;               // 0..7
  int hr  = wv >> 2;                // row within pair
  int wseg = (wv & 3) * 32;         // w window base
  int lj = l & 15, lg = l >> 4;

  f32x4 acc[8][2];
  #pragma unroll
  for (int i = 0; i < 8; ++i)
    #pragma unroll
    for (int j = 0; j < 2; ++j)
      acc[i][j] = (f32x4){0.f, 0.f, 0.f, 0.f};

  for (int ec = 0; ec < 4; ++ec) {
    const ushort* ub_ec = ubf + (((size_t)(bb*4 + ec)*66 + 2*h2 + hr)*130 + wseg + lj)*32 + lg*8;
    // prefetch all 18 B fragments for this ec; live across both o-halves
    short8v bfr[3][2][3];
    #pragma unroll
    for (int ki = 0; ki < 3; ++ki)
      #pragma unroll
      for (int f2 = 0; f2 < 2; ++f2)
        #pragma unroll
        for (int kj = 0; kj < 3; ++kj)
          bfr[ki][f2][kj] = *reinterpret_cast<const short8v*>(ub_ec + (size_t)ki*4160 + (f2*16 + kj)*32);

    #pragma unroll
    for (int half = 0; half < 2; ++half) {
      __syncthreads();
      const uint4* sA = reinterpret_cast<const uint4*>(wbf) + (size_t)((op*2 + half)*4 + ec)*2304;
      uint4* dA = reinterpret_cast<uint4*>(wlds);
      for (int q = tid; q < 2304; q += 512) dA[q] = sA[q];
      __syncthreads();

      #pragma unroll
      for (int ki = 0; ki < 3; ++ki) {
        #pragma unroll
        for (int kj = 0; kj < 3; ++kj) {
          const ushort* wtap = wlds + (ki*3 + kj)*2048 + l*8;
          short8v af[4];
          #pragma unroll
          for (int f = 0; f < 4; ++f)
            af[f] = *reinterpret_cast<const short8v*>(wtap + f*512);
          #pragma unroll
          for (int fo = 0; fo < 4; ++fo)
            #pragma unroll
            for (int fj = 0; fj < 2; ++fj)
              acc[half*4 + fo][fj] = __builtin_amdgcn_mfma_f32_16x16x32_bf16(af[fo], bfr[ki][fj][kj], acc[half*4 + fo][fj], 0, 0, 0);
        }
      }
    }
  }

  int row = h2*2 + hr;              // pre-shuffle output row, 0..63
  #pragma unroll
  for (int fo = 0; fo < 8; ++fo) {
    int obase = op*128 + fo*16 + lg*4;
    int g = obase >> 2;
    float b0 = cb[obase], b1 = cb[obase+1], b2 = cb[obase+2], b3 = cb[obase+3];
    size_t rbase0 = (((size_t)bb*128 + g)*128 + 2*row)*256;
    size_t rbase1 = rbase0 + 256;
    #pragma unroll
    for (int fj = 0; fj < 2; ++fj) {
      int w = wseg + fj*16 + lj;
      f32x4 a = acc[fo][fj];
      uint u0 = (uint)bf16rne(geluf(a.x + b0)) | ((uint)bf16rne(geluf(a.y + b1)) << 16);
      uint u1 = (uint)bf16rne(geluf(a.z + b2)) | ((uint)bf16rne(geluf(a.w + b3)) << 16);
      *reinterpret_cast<uint*>(cbf + rbase0 + 2*w) = u0;
      *reinterpret_cast<uint*>(cbf + rbase1 + 2*w) = u1;
    }
  }
}

// ---------------- FFN via bf16 MFMA: out = c + W2 @ gelu(W1 @ c + b1) + b2 (c from bf16 cbf) ----
__global__ __launch_bounds__(512) void k_ffnm(const ushort* __restrict__ wpad, const float* __restrict__ b1,
                                              const float* __restrict__ b2, const ushort* __restrict__ cbf,
                                              float* __restrict__ out){
  extern __shared__ ushort sm[];
  ushort* cT = sm;              // [128 px][136] bf16 c tile (survives to epilogue)
  ushort* wl = sm + 128*136;    // [128][136] bf16: W1, then f1[px][e]
  int pix0 = blockIdx.x * 128;  // 0..262143
  int bb = pix0 >> 15;
  int hw0 = pix0 & 32767;
  int tid = threadIdx.x;
  int l = tid & 63, wv = tid >> 6;
  int wc = wv >> 2, wp = wv & 3;
  int lj = l & 15, lg = l >> 4;
  int r = tid & 1, hpair = tid >> 1;      // for c staging
  const ushort* cbase = cbf + (size_t)bb*128*HW2 + hw0;

  for (int it = 0; it < 16; ++it) {
    int flat = it*256 + hpair;            // 0..4095
    int pp = flat & 63;                   // px-pair
    int cpair = flat >> 6;                // ch-pair
    int ch = cpair*2 + r;
    uint own = *reinterpret_cast<const uint*>(cbase + (size_t)ch*HW2 + pp*2);
    uint other = __shfl_xor((int)own, 1);
    uint o = r ? ((other >> 16) | (own & 0xffff0000u))
               : ((own & 0xffffu) | (other << 16));
    *reinterpret_cast<uint*>(&cT[(pp*2 + r)*136 + cpair*2]) = o;
  }
  {
    const uint4* src = reinterpret_cast<const uint4*>(wpad);
    uint4* dst = reinterpret_cast<uint4*>(wl);
    for (int i = tid; i < 2176; i += 512) dst[i] = src[i];
  }
  __syncthreads();

  f32x4 acc[4][2];
  #pragma unroll
  for (int fo = 0; fo < 4; ++fo)
    #pragma unroll
    for (int fj = 0; fj < 2; ++fj)
      acc[fo][fj] = (f32x4){0.f,0.f,0.f,0.f};

  #pragma unroll
  for (int kc = 0; kc < 4; ++kc) {
    short8v af[4], bq[2];
    #pragma unroll
    for (int fo = 0; fo < 4; ++fo)
      af[fo] = *reinterpret_cast<const short8v*>(&wl[(wc*64 + fo*16 + lj)*136 + kc*32 + lg*8]);
    #pragma unroll
    for (int fj = 0; fj < 2; ++fj)
      bq[fj] = *reinterpret_cast<const short8v*>(&cT[(wp*32 + fj*16 + lj)*136 + kc*32 + lg*8]);
    #pragma unroll
    for (int fo = 0; fo < 4; ++fo)
      #pragma unroll
      for (int fj = 0; fj < 2; ++fj)
        acc[fo][fj] = __builtin_amdgcn_mfma_f32_16x16x32_bf16(af[fo], bq[fj], acc[fo][fj], 0, 0, 0);
  }
  __syncthreads();

  const ushort* w2g = wpad + 17408;
  short8v a2[4], a2n[4];
  #pragma unroll
  for (int fo = 0; fo < 4; ++fo)
    a2[fo] = *reinterpret_cast<const short8v*>(w2g + (size_t)(wc*64 + fo*16 + lj)*136 + lg*8);

  #pragma unroll
  for (int fo = 0; fo < 4; ++fo) {
    int ch0 = wc*64 + fo*16 + lg*4;
    float c0 = b1[ch0], c1 = b1[ch0+1], c2 = b1[ch0+2], c3 = b1[ch0+3];
    #pragma unroll
    for (int fj = 0; fj < 2; ++fj) {
      int px = wp*32 + fj*16 + lj;
      f32x4 a = acc[fo][fj];
      uint2 u;
      u.x = (uint)bf16rne(geluf(a.x + c0)) | ((uint)bf16rne(geluf(a.y + c1)) << 16);
      u.y = (uint)bf16rne(geluf(a.z + c2)) | ((uint)bf16rne(geluf(a.w + c3)) << 16);
      *reinterpret_cast<uint2*>(&wl[px*136 + ch0]) = u;
    }
  }
  __syncthreads();

  #pragma unroll
  for (int fo = 0; fo < 4; ++fo)
    #pragma unroll
    for (int fj = 0; fj < 2; ++fj)
      acc[fo][fj] = (f32x4){0.f,0.f,0.f,0.f};

  #pragma unroll
  for (int kc = 0; kc < 4; ++kc) {
    if (kc < 3) {
      #pragma unroll
      for (int fo = 0; fo < 4; ++fo)
        a2n[fo] = *reinterpret_cast<const short8v*>(w2g + (size_t)(wc*64 + fo*16 + lj)*136 + (kc+1)*32 + lg*8);
    }
    short8v bq[2];
    #pragma unroll
    for (int fj = 0; fj < 2; ++fj)
      bq[fj] = *reinterpret_cast<const short8v*>(&wl[(wp*32 + fj*16 + lj)*136 + kc*32 + lg*8]);
    #pragma unroll
    for (int fo = 0; fo < 4; ++fo)
      #pragma unroll
      for (int fj = 0; fj < 2; ++fj)
        acc[fo][fj] = __builtin_amdgcn_mfma_f32_16x16x32_bf16(a2[fo], bq[fj], acc[fo][fj], 0, 0, 0);
    #pragma unroll
    for (int fo = 0; fo < 4; ++fo) a2[fo] = a2n[fo];
  }

  #pragma unroll
  for (int fo = 0; fo < 4; ++fo) {
    int ch0 = wc*64 + fo*16 + lg*4;
    float d0 = b2[ch0], d1 = b2[ch0+1], d2 = b2[ch0+2], d3 = b2[ch0+3];
    #pragma unroll
    for (int fj = 0; fj < 2; ++fj) {
      int px = wp*32 + fj*16 + lj;
      f32x4 a = acc[fo][fj];
      uint2 cu = *reinterpret_cast<const uint2*>(&cT[px*136 + ch0]);
      float cv0 = __uint_as_float((cu.x & 0xffffu) << 16);
      float cv1 = __uint_as_float(cu.x & 0xffff0000u);
      float cv2 = __uint_as_float((cu.y & 0xffffu) << 16);
      float cv3 = __uint_as_float(cu.y & 0xffff0000u);
      float* p0 = out + (size_t)bb*128*HW2 + (size_t)ch0*HW2 + hw0 + px;
      p0[0]             = cv0 + a.x + d0;
      p0[HW2]           = cv1 + a.y + d1;
      p0[2*HW2]         = cv2 + a.z + d2;
      p0[3*(size_t)HW2] = cv3 + a.w + d3;
    }
  }
}

extern "C" void kernel_launch(void* const* d_in, const int* in_sizes, int n_in,
                              void* d_out, int out_size, void* d_ws, size_t ws_size,
                              hipStream_t stream) {
  const float* x          = (const float*)d_in[0];
  const float* patch_w    = (const float*)d_in[1];
  const float* patch_b    = (const float*)d_in[2];
  const float* in_proj_w  = (const float*)d_in[3];
  const float* conv1d_w   = (const float*)d_in[4];
  const float* conv1d_b   = (const float*)d_in[5];
  const float* x_proj_w   = (const float*)d_in[6];
  const float* dt_proj_w  = (const float*)d_in[7];
  const float* dt_proj_b  = (const float*)d_in[8];
  const float* A_log      = (const float*)d_in[9];
  const float* D_param    = (const float*)d_in[10];
  const float* out_proj_w = (const float*)d_in[11];
  const float* lin_w      = (const float*)d_in[12];
  const float* lin_b      = (const float*)d_in[13];
  const float* conv_w     = (const float*)d_in[14];
  const float* conv_b     = (const float*)d_in[15];
  const float* ffn_w1     = (const float*)d_in[16];
  const float* ffn_b1     = (const float*)d_in[17];
  const float* ffn_w2     = (const float*)d_in[18];
  const float* ffn_b2     = (const float*)d_in[19];
  float* out = (float*)d_out;

  // ws_size = 512 MiB; generous layout.
  ushort* ubf  = (ushort*)d_ws;           // 10982400 bf16: [8][4][66][130][32]
  ushort* wbf  = ubf + 10982400;          // 589824 bf16 frag-linear conv weights
  ushort* wpad = wbf + 589824;            // 34816 bf16:    [2][128][136]
  float* t    = (float*)(wpad + 34816);   // 524288
  float* xz   = t    + 524288;            // 2097152
  float* xc   = xz   + 2097152;           // 1048576
  float* dbl  = xc   + 1048576;           // 163840
  float* dt   = dbl  + 163840;            // 1048576
  float* y    = dt   + 1048576;           // 1048576
  float* apr  = y    + 1048576;           // 524288
  float* hend = apr  + 524288;            // 524288
  ushort* lwbf = (ushort*)(hend + 524288);// 4194304 bf16
  ushort* ybfT = lwbf + 4194304;          // 524288 bf16
  ushort* cbf  = ybfT + 524288;           // 33554432 bf16 (64 MiB): [8][128][HW2]
  float* part = (float*)(cbf + 33554432); // 16*524288 floats (33.5 MiB)

  k_prep  <<<dim3(6568), dim3(256), 0, stream>>>((uint4*)ubf, conv_w, wbf, ffn_w1, ffn_w2, wpad, lin_w, lwbf);
  k_patchm<<<dim3(32, 16), dim3(256), 0, stream>>>(x, patch_w, part);
  k_tred  <<<dim3(512), dim3(256), 0, stream>>>(part, patch_b, t);
  k_iproj <<<dim3(32, 4), dim3(256), 0, stream>>>(t, in_proj_w, xz);
  k_cxp   <<<dim3(4096), dim3(256), 0, stream>>>(xz, conv1d_w, conv1d_b, x_proj_w, dt_proj_w, dt_proj_b, xc, dbl, dt);
  k_scanA <<<dim3(128, 16), dim3(256), 0, stream>>>(dt, dbl, xc, A_log, apr, hend);
  k_scanC <<<dim3(128, 16), dim3(256), 0, stream>>>(dt, dbl, xc, xz, A_log, D_param, apr, hend, y);
  k_oproj <<<dim3(64), dim3(256), 0, stream>>>(y, out_proj_w, ybfT);
  k_linm  <<<dim3(64, 8), dim3(512), 0, stream>>>(ybfT, lwbf, lin_b, ubf);
  k_conv3m<<<dim3(32, 32), dim3(512), 0, stream>>>(ubf, wbf, conv_b, cbf);
  k_ffnm  <<<dim3(2048), dim3(512), (size_t)(2*128*136)*sizeof(ushort), stream>>>(wpad, ffn_b1, ffn_b2, cbf, out);
}

// Round 16
// 301.001 us; speedup vs baseline: 1.1276x; 1.1276x over previous
//
#include <hip/hip_runtime.h>
#include <hip/hip_bf16.h>

// Shapes (fixed): B=8,C=256,H=64,W=128,P=4,E=DM=128,N=512,DI=256,DS=16,DC=4,DR=8,NG=128,S=2
#define HW2 32768   // 128*256 output spatial per (b,channel)

typedef __attribute__((ext_vector_type(8))) short short8v;
typedef __attribute__((ext_vector_type(4))) float f32x4;

__device__ __forceinline__ float siluf(float x){ return x / (1.f + __expf(-x)); }
__device__ __forceinline__ float geluf(float v){
  float t = 0.7978845608028654f * fmaf(0.044715f*v*v, v, v);
  t = fminf(fmaxf(t, -15.f), 15.f);
  float e = __expf(2.f*t);
  return 0.5f*v*(1.f + (e-1.f)/(e+1.f));
}
__device__ __forceinline__ ushort bf16rne(float f){
  unsigned u = __float_as_uint(f);
  unsigned r = (u + 0x7fffu + ((u >> 16) & 1u)) >> 16;
  return (ushort)r;
}
__device__ __forceinline__ float bf2f(ushort u){ return __uint_as_float(((unsigned)u) << 16); }
__device__ __forceinline__ void split2(float v, ushort& h, ushort& lo){
  h = bf16rne(v);
  lo = bf16rne(v - bf2f(h));
}

// ---------------- merged prep: ubf halo zero + conv/ffn/lin weight bf16 packs ----------------
__global__ __launch_bounds__(256) void k_prep(uint4* __restrict__ ubf4,
                                              const float* __restrict__ cw, ushort* __restrict__ wbf,
                                              const float* __restrict__ w1, const float* __restrict__ w2,
                                              ushort* __restrict__ wpad,
                                              const float* __restrict__ lw, ushort* __restrict__ lwbf){
  int bid = blockIdx.x;
  int tid = threadIdx.x;
  if (bid < 32) {                       // zero ubf halo borders
    uint4 z = make_uint4(0,0,0,0);
    size_t base4 = (size_t)bid * 34320;
    for (int i = tid; i < 1552; i += 256) {
      size_t off;
      if (i < 520)       off = i;
      else if (i < 1040) off = 33800 + (i - 520);
      else {
        int j = i - 1040;
        int row = 1 + (j >> 3);
        int colsel = (j >> 2) & 1, q = j & 3;
        off = (size_t)row*520 + colsel*516 + q;
      }
      ubf4[base4 + off] = z;
    }
  } else if (bid < 2336) {              // conv weights: frag-linear [(ocg*4+ec)][tap9][f4][lane64][8e]
    int idx = (bid - 32)*256 + tid;     // 589824
    int j    = idx & 7;
    int lane = (idx >> 3) & 63;
    int f    = (idx >> 9) & 3;
    int tap  = (idx >> 11) % 9;
    int rest = idx / 18432;
    int ec = rest & 3, ocg = rest >> 2;
    int o = ocg*64 + f*16 + (lane & 15);
    int e = ec*32 + (lane >> 4)*8 + j;
    wbf[idx] = bf16rne(cw[((size_t)o*128 + e)*9 + tap]);
  } else if (bid < 2472) {              // FFN weights padded [2][128][136]
    int idx = (bid - 2336)*256 + tid;   // 34816
    int which = idx / 17408;
    int rem = idx - which*17408;
    int e = rem / 136, k = rem - e*136;
    const float* s = which ? w2 : w1;
    wpad[idx] = (k < 128) ? bf16rne(s[e*128 + k]) : (ushort)0;
  } else {                              // lin weights bf16
    int i = (bid - 2472)*256 + tid;     // 1048576 float4s
    float4 v = reinterpret_cast<const float4*>(lw)[i];
    uint2 u;
    u.x = (uint)bf16rne(v.x) | ((uint)bf16rne(v.y) << 16);
    u.y = (uint)bf16rne(v.z) | ((uint)bf16rne(v.w) << 16);
    reinterpret_cast<uint2*>(lwbf)[i] = u;
  }
}

// ---------------- patch embed via bf16x3 MFMA, split-K=16 -> part[ks][4096][128] ----------------
__global__ __launch_bounds__(256) void k_patchm(const float* __restrict__ x, const float* __restrict__ pw,
                                                float* __restrict__ part){
  __shared__ ushort Ah[4096], Al[4096], Wh[4096], Wl[4096];  // frag-linear per 32-k chunk
  int m0 = blockIdx.x * 128;
  int ks = blockIdx.y;                 // 0..15
  int tid = threadIdx.x;
  int l = tid & 63, wv = tid >> 6;
  int wm = wv >> 1, we = wv & 1;
  int lj = l & 15, lg = l >> 4;
  f32x4 acc[4][4];
  #pragma unroll
  for (int a = 0; a < 4; ++a)
    #pragma unroll
    for (int b = 0; b < 4; ++b)
      acc[a][b] = (f32x4){0.f,0.f,0.f,0.f};
  int kbase = ks * 256;

  for (int it = 0; it < 8; ++it) {
    int k0 = kbase + it*32;
    __syncthreads();
    #pragma unroll
    for (int q = 0; q < 4; ++q) {
      int flat = q*256 + tid;
      int row = flat & 127, kk4 = flat >> 7;
      int m = m0 + row;
      int bb = m >> 9, ll = m & 511;
      int hp = ll >> 5, wp = ll & 31;
      int k = k0 + kk4*4;
      int c = k >> 4, i2 = (k >> 2) & 3;
      float4 v = *reinterpret_cast<const float4*>(x + (((bb*256 + c)*64 + hp*4 + i2)*128 + wp*4));
      ushort h0,h1,h2,h3,q0,q1,q2,q3;
      split2(v.x,h0,q0); split2(v.y,h1,q1); split2(v.z,h2,q2); split2(v.w,h3,q3);
      uint2 uh, ul;
      uh.x = (uint)h0 | ((uint)h1 << 16); uh.y = (uint)h2 | ((uint)h3 << 16);
      ul.x = (uint)q0 | ((uint)q1 << 16); ul.y = (uint)q2 | ((uint)q3 << 16);
      int lane = ((kk4 >> 1) << 4) | (row & 15);
      int dst = ((row >> 4)*64 + lane)*8 + (kk4 & 1)*4;
      *reinterpret_cast<uint2*>(Ah + dst) = uh;
      *reinterpret_cast<uint2*>(Al + dst) = ul;
    }
    #pragma unroll
    for (int q = 0; q < 4; ++q) {
      int flat = q*256 + tid;
      int e = flat >> 3, kk4 = flat & 7;
      float4 v = *reinterpret_cast<const float4*>(pw + (size_t)e*4096 + k0 + kk4*4);
      ushort h0,h1,h2,h3,q0,q1,q2,q3;
      split2(v.x,h0,q0); split2(v.y,h1,q1); split2(v.z,h2,q2); split2(v.w,h3,q3);
      uint2 uh, ul;
      uh.x = (uint)h0 | ((uint)h1 << 16); uh.y = (uint)h2 | ((uint)h3 << 16);
      ul.x = (uint)q0 | ((uint)q1 << 16); ul.y = (uint)q2 | ((uint)q3 << 16);
      int lane = ((kk4 >> 1) << 4) | (e & 15);
      int dst = ((e >> 4)*64 + lane)*8 + (kk4 & 1)*4;
      *reinterpret_cast<uint2*>(Wh + dst) = uh;
      *reinterpret_cast<uint2*>(Wl + dst) = ul;
    }
    __syncthreads();

    short8v ah[4], al_[4], wh[4], wl_[4];
    #pragma unroll
    for (int f = 0; f < 4; ++f) {
      ah[f]  = *reinterpret_cast<const short8v*>(Ah + ((wm*4 + f)*64 + l)*8);
      al_[f] = *reinterpret_cast<const short8v*>(Al + ((wm*4 + f)*64 + l)*8);
      wh[f]  = *reinterpret_cast<const short8v*>(Wh + ((we*4 + f)*64 + l)*8);
      wl_[f] = *reinterpret_cast<const short8v*>(Wl + ((we*4 + f)*64 + l)*8);
    }
    #pragma unroll
    for (int fo = 0; fo < 4; ++fo)
      #pragma unroll
      for (int fj = 0; fj < 4; ++fj) {
        acc[fo][fj] = __builtin_amdgcn_mfma_f32_16x16x32_bf16(ah[fo],  wh[fj],  acc[fo][fj], 0, 0, 0);
        acc[fo][fj] = __builtin_amdgcn_mfma_f32_16x16x32_bf16(ah[fo],  wl_[fj], acc[fo][fj], 0, 0, 0);
        acc[fo][fj] = __builtin_amdgcn_mfma_f32_16x16x32_bf16(al_[fo], wh[fj],  acc[fo][fj], 0, 0, 0);
      }
  }
  float* pb = part + (size_t)ks*524288;
  #pragma unroll
  for (int fo = 0; fo < 4; ++fo) {
    int m = m0 + wm*64 + fo*16 + lg*4;
    #pragma unroll
    for (int fj = 0; fj < 4; ++fj) {
      int e = we*64 + fj*16 + lj;
      f32x4 a = acc[fo][fj];
      pb[(size_t)(m+0)*128 + e] = a.x;
      pb[(size_t)(m+1)*128 + e] = a.y;
      pb[(size_t)(m+2)*128 + e] = a.z;
      pb[(size_t)(m+3)*128 + e] = a.w;
    }
  }
}

// ---------------- reduce 16 K-split partials + bias -> t ----------------
__global__ __launch_bounds__(256) void k_tred(const float* __restrict__ part, const float* __restrict__ pb,
                                              float* __restrict__ t){
  int i = blockIdx.x*256 + threadIdx.x;    // 131072 float4s
  const float4* p4 = reinterpret_cast<const float4*>(part);
  float4 s = reinterpret_cast<const float4*>(pb)[i & 31];
  #pragma unroll
  for (int ks = 0; ks < 16; ++ks) {
    float4 v = p4[(size_t)ks*131072 + i];
    s.x += v.x; s.y += v.y; s.z += v.z; s.w += v.w;
  }
  reinterpret_cast<float4*>(t)[i] = s;
}

// ---------------- in_proj via bf16x3 MFMA: xz(4096x512) = t(4096x128) @ W(512x128)^T ----------------
__global__ __launch_bounds__(256) void k_iproj(const float* __restrict__ t, const float* __restrict__ W,
                                               float* __restrict__ xz){
  __shared__ ushort Ah[4096], Al[4096], Wh[4096], Wl[4096];
  int m0 = blockIdx.x * 128;
  int n0 = blockIdx.y * 128;
  int tid = threadIdx.x;
  int l = tid & 63, wv = tid >> 6;
  int wm = wv >> 1, we = wv & 1;
  int lj = l & 15, lg = l >> 4;
  f32x4 acc[4][4];
  #pragma unroll
  for (int a = 0; a < 4; ++a)
    #pragma unroll
    for (int b = 0; b < 4; ++b)
      acc[a][b] = (f32x4){0.f,0.f,0.f,0.f};

  for (int it = 0; it < 4; ++it) {
    int k0 = it*32;
    __syncthreads();
    #pragma unroll
    for (int q = 0; q < 4; ++q) {
      int flat = q*256 + tid;
      int row = flat & 127, kk4 = flat >> 7;
      float4 v = *reinterpret_cast<const float4*>(t + (size_t)(m0 + row)*128 + k0 + kk4*4);
      ushort h0,h1,h2,h3,q0,q1,q2,q3;
      split2(v.x,h0,q0); split2(v.y,h1,q1); split2(v.z,h2,q2); split2(v.w,h3,q3);
      uint2 uh, ul;
      uh.x = (uint)h0 | ((uint)h1 << 16); uh.y = (uint)h2 | ((uint)h3 << 16);
      ul.x = (uint)q0 | ((uint)q1 << 16); ul.y = (uint)q2 | ((uint)q3 << 16);
      int lane = ((kk4 >> 1) << 4) | (row & 15);
      int dst = ((row >> 4)*64 + lane)*8 + (kk4 & 1)*4;
      *reinterpret_cast<uint2*>(Ah + dst) = uh;
      *reinterpret_cast<uint2*>(Al + dst) = ul;
    }
    #pragma unroll
    for (int q = 0; q < 4; ++q) {
      int flat = q*256 + tid;
      int e = flat >> 3, kk4 = flat & 7;
      float4 v = *reinterpret_cast<const float4*>(W + (size_t)(n0 + e)*128 + k0 + (kk4 & 7)*4);
      ushort h0,h1,h2,h3,q0,q1,q2,q3;
      split2(v.x,h0,q0); split2(v.y,h1,q1); split2(v.z,h2,q2); split2(v.w,h3,q3);
      uint2 uh, ul;
      uh.x = (uint)h0 | ((uint)h1 << 16); uh.y = (uint)h2 | ((uint)h3 << 16);
      ul.x = (uint)q0 | ((uint)q1 << 16); ul.y = (uint)q2 | ((uint)q3 << 16);
      int lane = ((kk4 >> 1) << 4) | (e & 15);
      int dst = ((e >> 4)*64 + lane)*8 + (kk4 & 1)*4;
      *reinterpret_cast<uint2*>(Wh + dst) = uh;
      *reinterpret_cast<uint2*>(Wl + dst) = ul;
    }
    __syncthreads();

    short8v ah[4], al_[4], wh[4], wl_[4];
    #pragma unroll
    for (int f = 0; f < 4; ++f) {
      ah[f]  = *reinterpret_cast<const short8v*>(Ah + ((wm*4 + f)*64 + l)*8);
      al_[f] = *reinterpret_cast<const short8v*>(Al + ((wm*4 + f)*64 + l)*8);
      wh[f]  = *reinterpret_cast<const short8v*>(Wh + ((we*4 + f)*64 + l)*8);
      wl_[f] = *reinterpret_cast<const short8v*>(Wl + ((we*4 + f)*64 + l)*8);
    }
    #pragma unroll
    for (int fo = 0; fo < 4; ++fo)
      #pragma unroll
      for (int fj = 0; fj < 4; ++fj) {
        acc[fo][fj] = __builtin_amdgcn_mfma_f32_16x16x32_bf16(ah[fo],  wh[fj],  acc[fo][fj], 0, 0, 0);
        acc[fo][fj] = __builtin_amdgcn_mfma_f32_16x16x32_bf16(ah[fo],  wl_[fj], acc[fo][fj], 0, 0, 0);
        acc[fo][fj] = __builtin_amdgcn_mfma_f32_16x16x32_bf16(al_[fo], wh[fj],  acc[fo][fj], 0, 0, 0);
      }
  }
  #pragma unroll
  for (int fo = 0; fo < 4; ++fo) {
    int m = m0 + wm*64 + fo*16 + lg*4;
    #pragma unroll
    for (int fj = 0; fj < 4; ++fj) {
      int n = n0 + we*64 + fj*16 + lj;
      f32x4 a = acc[fo][fj];
      xz[(size_t)(m+0)*512 + n] = a.x;
      xz[(size_t)(m+1)*512 + n] = a.y;
      xz[(size_t)(m+2)*512 + n] = a.z;
      xz[(size_t)(m+3)*512 + n] = a.w;
    }
  }
}

// ---------------- out_proj v2: m-tile 64, grid 64, 4 waves (wn x4, 64m x 32n each) ----------------
__global__ __launch_bounds__(256) void k_oproj(const float* __restrict__ y, const float* __restrict__ W,
                                               ushort* __restrict__ ybfT){
  __shared__ ushort Ah[2048], Al[2048], Wh[4096], Wl[4096];
  int m0 = blockIdx.x * 64;
  int tid = threadIdx.x;
  int l = tid & 63, wn = tid >> 6;     // wn 0..3
  int lj = l & 15, lg = l >> 4;
  f32x4 acc[4][2];
  #pragma unroll
  for (int a = 0; a < 4; ++a)
    #pragma unroll
    for (int b = 0; b < 2; ++b)
      acc[a][b] = (f32x4){0.f,0.f,0.f,0.f};

  for (int it = 0; it < 8; ++it) {
    int k0 = it*32;
    __syncthreads();
    #pragma unroll
    for (int q = 0; q < 2; ++q) {
      int flat = q*256 + tid;
      int row = flat & 63, kk4 = flat >> 6;
      float4 v = *reinterpret_cast<const float4*>(y + (size_t)(m0 + row)*256 + k0 + kk4*4);
      ushort h0,h1,h2,h3,q0,q1,q2,q3;
      split2(v.x,h0,q0); split2(v.y,h1,q1); split2(v.z,h2,q2); split2(v.w,h3,q3);
      uint2 uh, ul;
      uh.x = (uint)h0 | ((uint)h1 << 16); uh.y = (uint)h2 | ((uint)h3 << 16);
      ul.x = (uint)q0 | ((uint)q1 << 16); ul.y = (uint)q2 | ((uint)q3 << 16);
      int lane = ((kk4 >> 1) << 4) | (row & 15);
      int dst = ((row >> 4)*64 + lane)*8 + (kk4 & 1)*4;
      *reinterpret_cast<uint2*>(Ah + dst) = uh;
      *reinterpret_cast<uint2*>(Al + dst) = ul;
    }
    #pragma unroll
    for (int q = 0; q < 4; ++q) {
      int flat = q*256 + tid;
      int e = flat >> 3, kk4 = flat & 7;
      float4 v = *reinterpret_cast<const float4*>(W + (size_t)e*256 + k0 + kk4*4);
      ushort h0,h1,h2,h3,q0,q1,q2,q3;
      split2(v.x,h0,q0); split2(v.y,h1,q1); split2(v.z,h2,q2); split2(v.w,h3,q3);
      uint2 uh, ul;
      uh.x = (uint)h0 | ((uint)h1 << 16); uh.y = (uint)h2 | ((uint)h3 << 16);
      ul.x = (uint)q0 | ((uint)q1 << 16); ul.y = (uint)q2 | ((uint)q3 << 16);
      int lane = ((kk4 >> 1) << 4) | (e & 15);
      int dst = ((e >> 4)*64 + lane)*8 + (kk4 & 1)*4;
      *reinterpret_cast<uint2*>(Wh + dst) = uh;
      *reinterpret_cast<uint2*>(Wl + dst) = ul;
    }
    __syncthreads();

    short8v ah[4], al_[4], wh[2], wl_[2];
    #pragma unroll
    for (int f = 0; f < 4; ++f) {
      ah[f]  = *reinterpret_cast<const short8v*>(Ah + (f*64 + l)*8);
      al_[f] = *reinterpret_cast<const short8v*>(Al + (f*64 + l)*8);
    }
    #pragma unroll
    for (int f = 0; f < 2; ++f) {
      wh[f]  = *reinterpret_cast<const short8v*>(Wh + ((wn*2 + f)*64 + l)*8);
      wl_[f] = *reinterpret_cast<const short8v*>(Wl + ((wn*2 + f)*64 + l)*8);
    }
    #pragma unroll
    for (int fo = 0; fo < 4; ++fo)
      #pragma unroll
      for (int fj = 0; fj < 2; ++fj) {
        acc[fo][fj] = __builtin_amdgcn_mfma_f32_16x16x32_bf16(ah[fo],  wh[fj],  acc[fo][fj], 0, 0, 0);
        acc[fo][fj] = __builtin_amdgcn_mfma_f32_16x16x32_bf16(ah[fo],  wl_[fj], acc[fo][fj], 0, 0, 0);
        acc[fo][fj] = __builtin_amdgcn_mfma_f32_16x16x32_bf16(al_[fo], wh[fj],  acc[fo][fj], 0, 0, 0);
      }
  }
  #pragma unroll
  for (int fo = 0; fo < 4; ++fo) {
    int m = m0 + fo*16 + lg*4;
    int b = m >> 9, n = m & 511;
    #pragma unroll
    for (int fj = 0; fj < 2; ++fj) {
      int e = wn*32 + fj*16 + lj;
      f32x4 a = acc[fo][fj];
      uint2 u;
      u.x = (uint)bf16rne(a.x) | ((uint)bf16rne(a.y) << 16);
      u.y = (uint)bf16rne(a.z) | ((uint)bf16rne(a.w) << 16);
      *reinterpret_cast<uint2*>(ybfT + ((size_t)b*128 + e)*512 + n) = u;
    }
  }
}

// ---------------- fused conv1d+silu -> xc, then x_proj + dt_proj + softplus ----------------
__global__ __launch_bounds__(256) void k_cxp(const float* __restrict__ xz, const float* __restrict__ w1d,
                                             const float* __restrict__ c1b,
                                             const float* __restrict__ xpw,
                                             const float* __restrict__ dtw, const float* __restrict__ dtb,
                                             float* __restrict__ xc, float* __restrict__ dbl,
                                             float* __restrict__ dt){
  __shared__ __align__(16) float sxc[256];
  __shared__ float sdbl[40];
  int bl = blockIdx.x;         // (b,l) 0..4095
  int bb = bl >> 9, ll = bl & 511;
  int tid = threadIdx.x;
  float s = c1b[tid];
  #pragma unroll
  for (int k = 0; k < 4; ++k) {
    int ls = ll - 3 + k;
    if (ls >= 0) s = fmaf(xz[((size_t)(bb*512 + ls))*512 + tid], w1d[tid*4 + k], s);
  }
  float xcv = s / (1.f + __expf(-s));
  xc[(size_t)bl*256 + tid] = xcv;
  sxc[tid] = xcv;
  __syncthreads();
  if (tid < 160) {
    int g = tid >> 2, kq = tid & 3;
    const float4* wr = reinterpret_cast<const float4*>(xpw + g*256) + kq;
    const float4* xr = reinterpret_cast<const float4*>(sxc) + kq;
    float sv = 0.f;
    #pragma unroll
    for (int i = 0; i < 16; ++i) {
      float4 w = wr[i*4], xv = xr[i*4];
      sv += w.x*xv.x + w.y*xv.y + w.z*xv.z + w.w*xv.w;
    }
    sv += __shfl_xor(sv, 1);
    sv += __shfl_xor(sv, 2);
    if (kq == 0) {
      sdbl[g] = sv;
      dbl[(size_t)bl*40 + g] = sv;
    }
  }
  __syncthreads();
  float sd = dtb[tid];
  const float* wr = dtw + tid*8;
  #pragma unroll
  for (int r = 0; r < 8; ++r) sd = fmaf(sdbl[r], wr[r], sd);
  float sp = (sd > 20.f) ? sd : log1pf(__expf(sd));
  dt[(size_t)bl*256 + tid] = sp;
}

// ---------------- chunk-parallel selective scan (LDS-preloaded) ----------------
__global__ __launch_bounds__(256) void k_scanA(const float* __restrict__ dt, const float* __restrict__ dbl,
                                               const float* __restrict__ xc, const float* __restrict__ A_log,
                                               float* __restrict__ aprod, float* __restrict__ hend){
  __shared__ float sdt[32][16], sxc[32][16], sB[32][16];
  int tid = threadIdx.x;
  int bg = blockIdx.x;            // b*16 + dgrp
  int ch = blockIdx.y;
  int bb = bg >> 4, dgrp = bg & 15;
  int l0 = ch*32;
  #pragma unroll
  for (int it = 0; it < 2; ++it) {
    int idx = it*256 + tid;       // 0..511
    int t = idx >> 4, dd = idx & 15;
    int base = bb*512 + l0 + t;
    sdt[t][dd] = dt[(size_t)base*256 + dgrp*16 + dd];
    sxc[t][dd] = xc[(size_t)base*256 + dgrp*16 + dd];
    sB [t][dd] = dbl[(size_t)base*40 + 8 + dd];
  }
  __syncthreads();
  int n = tid & 15, dloc = tid >> 4;
  float Ac = -__expf(A_log[(dgrp*16 + dloc)*16 + n]);
  float a = 1.f, h = 0.f;
  #pragma unroll
  for (int t = 0; t < 32; ++t) {
    float dtv = sdt[t][dloc], xcv = sxc[t][dloc], Bv = sB[t][n];
    float dA = __expf(dtv*Ac);
    h = fmaf(dA, h, dtv*Bv*xcv);
    a *= dA;
  }
  aprod[(size_t)(bg*16 + ch)*256 + tid] = a;
  hend [(size_t)(bg*16 + ch)*256 + tid] = h;
}

// scanC with fused cross-chunk prefix
__global__ __launch_bounds__(256) void k_scanC(const float* __restrict__ dt, const float* __restrict__ dbl,
                                               const float* __restrict__ xc, const float* __restrict__ xz,
                                               const float* __restrict__ A_log, const float* __restrict__ Dp,
                                               const float* __restrict__ aprod, const float* __restrict__ hend,
                                               float* __restrict__ y){
  __shared__ float sdt[32][16], sxc[32][16], sB[32][16], sC[32][16], sz[32][16];
  int tid = threadIdx.x;
  int bg = blockIdx.x;
  int ch = blockIdx.y;
  int bb = bg >> 4, dgrp = bg & 15;
  int l0 = ch*32;
  #pragma unroll
  for (int it = 0; it < 2; ++it) {
    int idx = it*256 + tid;
    int t = idx >> 4, dd = idx & 15;
    int base = bb*512 + l0 + t;
    sdt[t][dd] = dt[(size_t)base*256 + dgrp*16 + dd];
    sxc[t][dd] = xc[(size_t)base*256 + dgrp*16 + dd];
    sB [t][dd] = dbl[(size_t)base*40 + 8  + dd];
    sC [t][dd] = dbl[(size_t)base*40 + 24 + dd];
    sz [t][dd] = xz[(size_t)base*512 + 256 + dgrp*16 + dd];
  }
  float h = 0.f;
  for (int cc = 0; cc < ch; ++cc) {
    size_t idx = (size_t)(bg*16 + cc)*256 + tid;
    h = fmaf(aprod[idx], h, hend[idx]);
  }
  __syncthreads();
  int n = tid & 15, dloc = tid >> 4;
  int d = dgrp*16 + dloc;
  float Ac = -__expf(A_log[d*16 + n]);
  float Dv = Dp[d];
  #pragma unroll 4
  for (int t = 0; t < 32; ++t) {
    float dtv = sdt[t][dloc], xcv = sxc[t][dloc];
    float Bv = sB[t][n], Cv = sC[t][n];
    float dA = __expf(dtv*Ac);
    h = fmaf(dA, h, dtv*Bv*xcv);
    float yp = h*Cv;
    yp += __shfl_xor(yp, 1, 16);
    yp += __shfl_xor(yp, 2, 16);
    yp += __shfl_xor(yp, 4, 16);
    yp += __shfl_xor(yp, 8, 16);
    if (n == 0) {
      float zv = sz[t][dloc];
      y[(size_t)(bb*512 + l0 + t)*256 + d] = (yp + Dv*xcv) * (zv / (1.f + __expf(-zv)));
    }
  }
}

// ---------------- lin via bf16 MFMA + bias + pixel-shuffle -> padded bf16 ubf ----------------
__global__ __launch_bounds__(512) void k_linm(const ushort* __restrict__ ybfT, const ushort* __restrict__ lwbf,
                                              const float* __restrict__ lb, ushort* __restrict__ ubf){
  __shared__ ushort As[128*88];
  __shared__ ushort Bs[128*88];
  int m0 = blockIdx.x * 128;
  int b  = blockIdx.y;
  int tid = threadIdx.x;
  int l = tid & 63, wv = tid >> 6;
  int wm = wv & 3, we = wv >> 2;
  int lj = l & 15, lg = l >> 4;
  f32x4 acc[4][2];
  #pragma unroll
  for (int fo = 0; fo < 4; ++fo)
    #pragma unroll
    for (int fj = 0; fj < 2; ++fj)
      acc[fo][fj] = (f32x4){0.f,0.f,0.f,0.f};

  for (int k0 = 0; k0 < 512; k0 += 64) {
    __syncthreads();
    #pragma unroll
    for (int it = 0; it < 2; ++it) {
      int flat = it*512 + tid;        // 0..1023
      int e = flat >> 3, kc8 = flat & 7;
      *reinterpret_cast<uint4*>(&As[e*88 + kc8*8]) =
        *reinterpret_cast<const uint4*>(ybfT + ((size_t)b*128 + e)*512 + k0 + kc8*8);
      *reinterpret_cast<uint4*>(&Bs[e*88 + kc8*8]) =
        *reinterpret_cast<const uint4*>(lwbf + (size_t)(m0 + e)*512 + k0 + kc8*8);
    }
    __syncthreads();
    #pragma unroll
    for (int kc = 0; kc < 2; ++kc) {
      short8v af[4], bq[2];
      #pragma unroll
      for (int fo = 0; fo < 4; ++fo)
        af[fo] = *reinterpret_cast<const short8v*>(&As[(we*64 + fo*16 + lj)*88 + kc*32 + lg*8]);
      #pragma unroll
      for (int fj = 0; fj < 2; ++fj)
        bq[fj] = *reinterpret_cast<const short8v*>(&Bs[(wm*32 + fj*16 + lj)*88 + kc*32 + lg*8]);
      #pragma unroll
      for (int fo = 0; fo < 4; ++fo)
        #pragma unroll
        for (int fj = 0; fj < 2; ++fj)
          acc[fo][fj] = __builtin_amdgcn_mfma_f32_16x16x32_bf16(af[fo], bq[fj], acc[fo][fj], 0, 0, 0);
    }
  }
  #pragma unroll
  for (int fj = 0; fj < 2; ++fj) {
    int m = m0 + wm*32 + fj*16 + lj;
    float bias = lb[m];
    int hh = ((m >> 9) << 2) + ((m >> 2) & 3);
    int ww = (((m >> 4) & 31) << 2) + (m & 3);
    #pragma unroll
    for (int fo = 0; fo < 4; ++fo) {
      int eg = we*2 + (fo >> 1);
      int e5 = ((fo & 1) << 4) + (lg << 2);
      f32x4 a = acc[fo][fj];
      uint2 u;
      u.x = (uint)bf16rne(a.x + bias) | ((uint)bf16rne(a.y + bias) << 16);
      u.y = (uint)bf16rne(a.z + bias) | ((uint)bf16rne(a.w + bias) << 16);
      *reinterpret_cast<uint2*>(ubf + ((((size_t)b*4 + eg)*66 + hh + 1)*130 + ww + 1)*32 + e5) = u;
    }
  }
}

// ---------------- conv3x3 (r14 proven config): 8 waves, 128o x 32w, weights in LDS, B from L2 ----------------
// grid (h2=32, bz=32: bb*4+op). 512 thr = 8 waves (2hr x 4wseg32).
__global__ __launch_bounds__(512, 2) void k_conv3m(const ushort* __restrict__ ubf, const ushort* __restrict__ wbf,
                                                   const float* __restrict__ cb, ushort* __restrict__ cbf){
  __shared__ ushort wlds[36864];    // [2 half][9 tap][4 f][64 lane][8 e] for current ec (73.7 KB)
  int h2 = blockIdx.x;              // 0..31
  int bz = blockIdx.y;
  int bb = bz >> 2, op = bz & 3;    // batch, 128-o pair
  int tid = threadIdx.x;
  int l   = tid & 63;
  int wv  = tid >> 6;               // 0..7
  int hr  = wv >> 2;                // row within pair
  int wseg = (wv & 3) * 32;         // w window base
  int lj = l & 15, lg = l >> 4;

  f32x4 acc[8][2];
  #pragma unroll
  for (int i = 0; i < 8; ++i)
    #pragma unroll
    for (int j = 0; j < 2; ++j)
      acc[i][j] = (f32x4){0.f, 0.f, 0.f, 0.f};

  for (int ec = 0; ec < 4; ++ec) {
    __syncthreads();
    const uint4* s0 = reinterpret_cast<const uint4*>(wbf) + (size_t)((op*2    )*4 + ec)*2304;
    const uint4* s1 = reinterpret_cast<const uint4*>(wbf) + (size_t)((op*2 + 1)*4 + ec)*2304;
    uint4* dA = reinterpret_cast<uint4*>(wlds);
    for (int q = tid; q < 2304; q += 512) { dA[q] = s0[q]; dA[2304 + q] = s1[q]; }
    __syncthreads();

    const ushort* ub_ec = ubf + (((size_t)(bb*4 + ec)*66 + 2*h2 + hr)*130 + wseg + lj)*32 + lg*8;
    short8v bfr[3][2][3];
    #pragma unroll
    for (int ki = 0; ki < 3; ++ki)
      #pragma unroll
      for (int f2 = 0; f2 < 2; ++f2)
        #pragma unroll
        for (int kj = 0; kj < 3; ++kj)
          bfr[ki][f2][kj] = *reinterpret_cast<const short8v*>(ub_ec + (size_t)ki*4160 + (f2*16 + kj)*32);

    #pragma unroll
    for (int ki = 0; ki < 3; ++ki) {
      #pragma unroll
      for (int kj = 0; kj < 3; ++kj) {
        const ushort* wtap0 = wlds + (ki*3 + kj)*2048 + l*8;
        #pragma unroll
        for (int half = 0; half < 2; ++half) {
          const ushort* wtap = wtap0 + half*18432;
          short8v af[4];
          #pragma unroll
          for (int f = 0; f < 4; ++f)
            af[f] = *reinterpret_cast<const short8v*>(wtap + f*512);
          #pragma unroll
          for (int fo = 0; fo < 4; ++fo)
            #pragma unroll
            for (int fj = 0; fj < 2; ++fj)
              acc[half*4 + fo][fj] = __builtin_amdgcn_mfma_f32_16x16x32_bf16(af[fo], bfr[ki][fj][kj], acc[half*4 + fo][fj], 0, 0, 0);
        }
      }
    }
  }

  int row = h2*2 + hr;              // pre-shuffle output row, 0..63
  #pragma unroll
  for (int fo = 0; fo < 8; ++fo) {
    int obase = op*128 + fo*16 + lg*4;
    int g = obase >> 2;
    float b0 = cb[obase], b1 = cb[obase+1], b2 = cb[obase+2], b3 = cb[obase+3];
    size_t rbase0 = (((size_t)bb*128 + g)*128 + 2*row)*256;
    size_t rbase1 = rbase0 + 256;
    #pragma unroll
    for (int fj = 0; fj < 2; ++fj) {
      int w = wseg + fj*16 + lj;
      f32x4 a = acc[fo][fj];
      uint u0 = (uint)bf16rne(geluf(a.x + b0)) | ((uint)bf16rne(geluf(a.y + b1)) << 16);
      uint u1 = (uint)bf16rne(geluf(a.z + b2)) | ((uint)bf16rne(geluf(a.w + b3)) << 16);
      *reinterpret_cast<uint*>(cbf + rbase0 + 2*w) = u0;
      *reinterpret_cast<uint*>(cbf + rbase1 + 2*w) = u1;
    }
  }
}

// ---------------- FFN via bf16 MFMA: out = c + W2 @ gelu(W1 @ c + b1) + b2 (c from bf16 cbf) ----
__global__ __launch_bounds__(512) void k_ffnm(const ushort* __restrict__ wpad, const float* __restrict__ b1,
                                              const float* __restrict__ b2, const ushort* __restrict__ cbf,
                                              float* __restrict__ out){
  extern __shared__ ushort sm[];
  ushort* cT = sm;              // [128 px][136] bf16 c tile (survives to epilogue)
  ushort* wl = sm + 128*136;    // [128][136] bf16: W1, then f1[px][e]
  int pix0 = blockIdx.x * 128;  // 0..262143
  int bb = pix0 >> 15;
  int hw0 = pix0 & 32767;
  int tid = threadIdx.x;
  int l = tid & 63, wv = tid >> 6;
  int wc = wv >> 2, wp = wv & 3;
  int lj = l & 15, lg = l >> 4;
  int r = tid & 1, hpair = tid >> 1;      // for c staging
  const ushort* cbase = cbf + (size_t)bb*128*HW2 + hw0;

  for (int it = 0; it < 16; ++it) {
    int flat = it*256 + hpair;            // 0..4095
    int pp = flat & 63;                   // px-pair
    int cpair = flat >> 6;                // ch-pair
    int ch = cpair*2 + r;
    uint own = *reinterpret_cast<const uint*>(cbase + (size_t)ch*HW2 + pp*2);
    uint other = __shfl_xor((int)own, 1);
    uint o = r ? ((other >> 16) | (own & 0xffff0000u))
               : ((own & 0xffffu) | (other << 16));
    *reinterpret_cast<uint*>(&cT[(pp*2 + r)*136 + cpair*2]) = o;
  }
  {
    const uint4* src = reinterpret_cast<const uint4*>(wpad);
    uint4* dst = reinterpret_cast<uint4*>(wl);
    for (int i = tid; i < 2176; i += 512) dst[i] = src[i];
  }
  __syncthreads();

  f32x4 acc[4][2];
  #pragma unroll
  for (int fo = 0; fo < 4; ++fo)
    #pragma unroll
    for (int fj = 0; fj < 2; ++fj)
      acc[fo][fj] = (f32x4){0.f,0.f,0.f,0.f};

  #pragma unroll
  for (int kc = 0; kc < 4; ++kc) {
    short8v af[4], bq[2];
    #pragma unroll
    for (int fo = 0; fo < 4; ++fo)
      af[fo] = *reinterpret_cast<const short8v*>(&wl[(wc*64 + fo*16 + lj)*136 + kc*32 + lg*8]);
    #pragma unroll
    for (int fj = 0; fj < 2; ++fj)
      bq[fj] = *reinterpret_cast<const short8v*>(&cT[(wp*32 + fj*16 + lj)*136 + kc*32 + lg*8]);
    #pragma unroll
    for (int fo = 0; fo < 4; ++fo)
      #pragma unroll
      for (int fj = 0; fj < 2; ++fj)
        acc[fo][fj] = __builtin_amdgcn_mfma_f32_16x16x32_bf16(af[fo], bq[fj], acc[fo][fj], 0, 0, 0);
  }
  __syncthreads();

  const ushort* w2g = wpad + 17408;
  short8v a2[4], a2n[4];
  #pragma unroll
  for (int fo = 0; fo < 4; ++fo)
    a2[fo] = *reinterpret_cast<const short8v*>(w2g + (size_t)(wc*64 + fo*16 + lj)*136 + lg*8);

  #pragma unroll
  for (int fo = 0; fo < 4; ++fo) {
    int ch0 = wc*64 + fo*16 + lg*4;
    float c0 = b1[ch0], c1 = b1[ch0+1], c2 = b1[ch0+2], c3 = b1[ch0+3];
    #pragma unroll
    for (int fj = 0; fj < 2; ++fj) {
      int px = wp*32 + fj*16 + lj;
      f32x4 a = acc[fo][fj];
      uint2 u;
      u.x = (uint)bf16rne(geluf(a.x + c0)) | ((uint)bf16rne(geluf(a.y + c1)) << 16);
      u.y = (uint)bf16rne(geluf(a.z + c2)) | ((uint)bf16rne(geluf(a.w + c3)) << 16);
      *reinterpret_cast<uint2*>(&wl[px*136 + ch0]) = u;
    }
  }
  __syncthreads();

  #pragma unroll
  for (int fo = 0; fo < 4; ++fo)
    #pragma unroll
    for (int fj = 0; fj < 2; ++fj)
      acc[fo][fj] = (f32x4){0.f,0.f,0.f,0.f};

  #pragma unroll
  for (int kc = 0; kc < 4; ++kc) {
    if (kc < 3) {
      #pragma unroll
      for (int fo = 0; fo < 4; ++fo)
        a2n[fo] = *reinterpret_cast<const short8v*>(w2g + (size_t)(wc*64 + fo*16 + lj)*136 + (kc+1)*32 + lg*8);
    }
    short8v bq[2];
    #pragma unroll
    for (int fj = 0; fj < 2; ++fj)
      bq[fj] = *reinterpret_cast<const short8v*>(&wl[(wp*32 + fj*16 + lj)*136 + kc*32 + lg*8]);
    #pragma unroll
    for (int fo = 0; fo < 4; ++fo)
      #pragma unroll
      for (int fj = 0; fj < 2; ++fj)
        acc[fo][fj] = __builtin_amdgcn_mfma_f32_16x16x32_bf16(a2[fo], bq[fj], acc[fo][fj], 0, 0, 0);
    #pragma unroll
    for (int fo = 0; fo < 4; ++fo) a2[fo] = a2n[fo];
  }

  #pragma unroll
  for (int fo = 0; fo < 4; ++fo) {
    int ch0 = wc*64 + fo*16 + lg*4;
    float d0 = b2[ch0], d1 = b2[ch0+1], d2 = b2[ch0+2], d3 = b2[ch0+3];
    #pragma unroll
    for (int fj = 0; fj < 2; ++fj) {
      int px = wp*32 + fj*16 + lj;
      f32x4 a = acc[fo][fj];
      uint2 cu = *reinterpret_cast<const uint2*>(&cT[px*136 + ch0]);
      float cv0 = __uint_as_float((cu.x & 0xffffu) << 16);
      float cv1 = __uint_as_float(cu.x & 0xffff0000u);
      float cv2 = __uint_as_float((cu.y & 0xffffu) << 16);
      float cv3 = __uint_as_float(cu.y & 0xffff0000u);
      float* p0 = out + (size_t)bb*128*HW2 + (size_t)ch0*HW2 + hw0 + px;
      p0[0]             = cv0 + a.x + d0;
      p0[HW2]           = cv1 + a.y + d1;
      p0[2*HW2]         = cv2 + a.z + d2;
      p0[3*(size_t)HW2] = cv3 + a.w + d3;
    }
  }
}

extern "C" void kernel_launch(void* const* d_in, const int* in_sizes, int n_in,
                              void* d_out, int out_size, void* d_ws, size_t ws_size,
                              hipStream_t stream) {
  const float* x          = (const float*)d_in[0];
  const float* patch_w    = (const float*)d_in[1];
  const float* patch_b    = (const float*)d_in[2];
  const float* in_proj_w  = (const float*)d_in[3];
  const float* conv1d_w   = (const float*)d_in[4];
  const float* conv1d_b   = (const float*)d_in[5];
  const float* x_proj_w   = (const float*)d_in[6];
  const float* dt_proj_w  = (const float*)d_in[7];
  const float* dt_proj_b  = (const float*)d_in[8];
  const float* A_log      = (const float*)d_in[9];
  const float* D_param    = (const float*)d_in[10];
  const float* out_proj_w = (const float*)d_in[11];
  const float* lin_w      = (const float*)d_in[12];
  const float* lin_b      = (const float*)d_in[13];
  const float* conv_w     = (const float*)d_in[14];
  const float* conv_b     = (const float*)d_in[15];
  const float* ffn_w1     = (const float*)d_in[16];
  const float* ffn_b1     = (const float*)d_in[17];
  const float* ffn_w2     = (const float*)d_in[18];
  const float* ffn_b2     = (const float*)d_in[19];
  float* out = (float*)d_out;

  // ws_size = 512 MiB; generous layout.
  ushort* ubf  = (ushort*)d_ws;           // 10982400 bf16: [8][4][66][130][32]
  ushort* wbf  = ubf + 10982400;          // 589824 bf16 frag-linear conv weights
  ushort* wpad = wbf + 589824;            // 34816 bf16:    [2][128][136]
  float* t    = (float*)(wpad + 34816);   // 524288
  float* xz   = t    + 524288;            // 2097152
  float* xc   = xz   + 2097152;           // 1048576
  float* dbl  = xc   + 1048576;           // 163840
  float* dt   = dbl  + 163840;            // 1048576
  float* y    = dt   + 1048576;           // 1048576
  float* apr  = y    + 1048576;           // 524288
  float* hend = apr  + 524288;            // 524288
  ushort* lwbf = (ushort*)(hend + 524288);// 4194304 bf16
  ushort* ybfT = lwbf + 4194304;          // 524288 bf16
  ushort* cbf  = ybfT + 524288;           // 33554432 bf16 (64 MiB): [8][128][HW2]
  float* part = (float*)(cbf + 33554432); // 16*524288 floats (33.5 MiB)

  k_prep  <<<dim3(6568), dim3(256), 0, stream>>>((uint4*)ubf, conv_w, wbf, ffn_w1, ffn_w2, wpad, lin_w, lwbf);
  k_patchm<<<dim3(32, 16), dim3(256), 0, stream>>>(x, patch_w, part);
  k_tred  <<<dim3(512), dim3(256), 0, stream>>>(part, patch_b, t);
  k_iproj <<<dim3(32, 4), dim3(256), 0, stream>>>(t, in_proj_w, xz);
  k_cxp   <<<dim3(4096), dim3(256), 0, stream>>>(xz, conv1d_w, conv1d_b, x_proj_w, dt_proj_w, dt_proj_b, xc, dbl, dt);
  k_scanA <<<dim3(128, 16), dim3(256), 0, stream>>>(dt, dbl, xc, A_log, apr, hend);
  k_scanC <<<dim3(128, 16), dim3(256), 0, stream>>>(dt, dbl, xc, xz, A_log, D_param, apr, hend, y);
  k_oproj <<<dim3(64), dim3(256), 0, stream>>>(y, out_proj_w, ybfT);
  k_linm  <<<dim3(64, 8), dim3(512), 0, stream>>>(ybfT, lwbf, lin_b, ubf);
  k_conv3m<<<dim3(32, 32), dim3(512), 0, stream>>>(ubf, wbf, conv_b, cbf);
  k_ffnm  <<<dim3(2048), dim3(512), (size_t)(2*128*136)*sizeof(ushort), stream>>>(wpad, ffn_b1, ffn_b2, cbf, out);
}